// Round 6
// baseline (585.904 us; speedup 1.0000x reference)
//
#include <hip/hip_runtime.h>
#include <hip/hip_bf16.h>
#include <math.h>

#define Z 512
#define XV 10000
#define SEQ 256
#define NB 64
#define KT_LDS 4               // k-tiles (K=32 each) staged in LDS
#define KT_TOT 16              // total k-tiles

typedef short bf16x8 __attribute__((ext_vector_type(8)));
typedef float f32x4  __attribute__((ext_vector_type(4)));
typedef unsigned u32x4 __attribute__((ext_vector_type(4)));

__device__ __forceinline__ unsigned short bf16_bits(float a) {
    return __builtin_bit_cast(unsigned short, __float2bfloat16(a));
}
__device__ __forceinline__ unsigned pack_bf2(float a, float b) {
    return ((unsigned)bf16_bits(b) << 16) | (unsigned)bf16_bits(a);
}
__device__ __forceinline__ void online_combine(float& m, float& s, float pm, float ps) {
    if (pm > m) { s = s * __expf(m - pm) + ps; m = pm; }
    else        { s = s + ps * __expf(pm - m); }
}

// ---- prepA: blocks 0..7 = column-LSE of T; blocks 8..263 = emit column-LSE partials
__global__ void k_prepA(const float* __restrict__ T, const float* __restrict__ emit,
                        float* __restrict__ colLSE, float2* __restrict__ em_part) {
    __shared__ float ms[256], ss[256];
    const int tid = threadIdx.x;
    const int cl = tid & 63;
    const int r0 = tid >> 6;
    float m = -INFINITY, s = 0.f;
    int outc;
    if (blockIdx.x < 8) {
        const int c = blockIdx.x * 64 + cl;
        for (int r = r0; r < Z; r += 4)
            online_combine(m, s, T[(size_t)r * Z + c], 1.f);
        outc = 0;
    } else {
        const int bb = blockIdx.x - 8;
        const int g = bb & 7, rg = bb >> 3;
        const int c = g * 64 + cl;
        const int rstart = rg * 313;
        const int rend = (rstart + 313 < XV) ? rstart + 313 : XV;
        for (int r = rstart + r0; r < rend; r += 4)
            online_combine(m, s, emit[(size_t)r * Z + c], 1.f);
        outc = 1;
    }
    ms[tid] = m; ss[tid] = s;
    __syncthreads();
    if (tid < 128) {
        m = ms[tid]; s = ss[tid];
        online_combine(m, s, ms[tid + 128], ss[tid + 128]);
        ms[tid] = m; ss[tid] = s;
    }
    __syncthreads();
    if (tid < 64) {
        m = ms[tid]; s = ss[tid];
        online_combine(m, s, ms[tid + 64], ss[tid + 64]);
        if (outc == 0) {
            colLSE[blockIdx.x * 64 + tid] = m + __logf(s);
        } else {
            const int bb = blockIdx.x - 8;
            em_part[(size_t)(bb >> 3) * Z + (bb & 7) * 64 + tid] = make_float2(m, s);
        }
    }
}

// ---- prepB: blocks 0..511 = build bf16 E-matrix row j (+ mTj); block 512 = finalize
__global__ void k_prepB(const float* __restrict__ T, const float* __restrict__ colLSE,
                        const float2* __restrict__ em_part, const float* __restrict__ pi,
                        unsigned short* __restrict__ H, float* __restrict__ mTj,
                        float* __restrict__ emit_lse, float* __restrict__ pi_eff) {
    __shared__ float sh[512];
    const int tid = threadIdx.x;
    if (blockIdx.x < Z) {
        const int j = blockIdx.x;
        const float v = T[(size_t)j * Z + tid] - colLSE[tid];
        float mv = v;
        #pragma unroll
        for (int off = 32; off > 0; off >>= 1) mv = fmaxf(mv, __shfl_xor(mv, off));
        if ((tid & 63) == 0) sh[tid >> 6] = mv;
        __syncthreads();
        float mT = sh[0];
        #pragma unroll
        for (int q = 1; q < 8; ++q) mT = fmaxf(mT, sh[q]);
        H[(size_t)(tid >> 1) * 1024 + 2 * j + (tid & 1)] = bf16_bits(__expf(v - mT));
        if (tid == 0) mTj[j] = mT;
    } else {
        const int z = tid;
        float m = -INFINITY, s = 0.f;
        for (int rg = 0; rg < 32; ++rg) {
            float2 p = em_part[(size_t)rg * Z + z];
            online_combine(m, s, p.x, p.y);
        }
        const float el = m + __logf(s);
        emit_lse[z] = el;
        const float v = pi[z];
        sh[z] = v; __syncthreads();
        for (int off = 256; off > 0; off >>= 1) {
            if (z < off) sh[z] = fmaxf(sh[z], sh[z + off]);
            __syncthreads();
        }
        const float mx = sh[0];
        __syncthreads();
        sh[z] = __expf(v - mx); __syncthreads();
        for (int off = 256; off > 0; off >>= 1) {
            if (z < off) sh[z] += sh[z + off];
            __syncthreads();
        }
        pi_eff[z] = (v - (mx + __logf(sh[0]))) - el;
    }
}

// ---- scan: 64 blocks (one batch each), 512 threads, MFMA matvec,
// ONE barrier per step. ea scaled per-source-wave; consumer recombines with
// wexp[w] = exp(m_w - M) read from prev step's redm (off critical path).
__global__ void __launch_bounds__(512, 2)
k_hmm_scan(const int* __restrict__ ids, const float* __restrict__ emit,
           const unsigned* __restrict__ Mbuf, const float* __restrict__ mTj,
           const float* __restrict__ emit_lse, const float* __restrict__ pi_eff,
           float* __restrict__ out)
{
    extern __shared__ unsigned dynlds[];
    unsigned* lds_B   = dynlds;                        // 32768 dw = 128 KB
    unsigned* lds_ea  = dynlds + 32768;                // [2][256] dw
    float*    redm    = (float*)(dynlds + 33280);      // [2][8]
    float*    redf    = (float*)(dynlds + 33296);      // [8]
    int*      lds_ids = (int*)(dynlds + 33304);        // [256]

    const int b = blockIdx.x;
    const int tid = threadIdx.x;
    const int w = tid >> 6, lane = tid & 63;
    const int g = lane >> 4;                           // k-subgroup 0..3
    const int c = lane & 15;                           // column-in-tile
    const int jbase = 64 * w;

    if (tid < SEQ) lds_ids[tid] = ids[tid * NB + b];

    // ---- stage B: LDS k-tiles (kt 0..3), each wave stages its own j-slice
    #pragma unroll
    for (int kt = 0; kt < KT_LDS; ++kt)
        #pragma unroll
        for (int nt = 0; nt < 4; ++nt) {
            const unsigned* src = Mbuf + (size_t)(kt * 16 + g * 4) * Z + jbase + nt * 16 + c;
            u32x4 v = { src[0], src[Z], src[2 * Z], src[3 * Z] };
            *(u32x4*)(lds_B + ((w * KT_LDS + kt) * 4 + nt) * 256 + lane * 4) = v;
        }
    // ---- stage B: register k-tiles (kt 4..15)
    u32x4 breg[KT_TOT - KT_LDS][4];
    #pragma unroll
    for (int kt = 0; kt < KT_TOT - KT_LDS; ++kt)
        #pragma unroll
        for (int nt = 0; nt < 4; ++nt) {
            const unsigned* src =
                Mbuf + (size_t)((KT_LDS + kt) * 16 + g * 4) * Z + jbase + nt * 16 + c;
            breg[kt][nt] = (u32x4){ src[0], src[Z], src[2 * Z], src[3 * Z] };
        }

    // ---- init alpha0 (replicated across g-groups)
    const int id0 = ids[b];
    float alpha[4], adjj[4];
    #pragma unroll
    for (int nt = 0; nt < 4; ++nt) {
        const int j = jbase + nt * 16 + c;
        adjj[nt] = mTj[j] - emit_lse[j];
        alpha[nt] = emit[(size_t)id0 * Z + j] + pi_eff[j];
    }
    {
        float mv = fmaxf(fmaxf(alpha[0], alpha[1]), fmaxf(alpha[2], alpha[3]));
        #pragma unroll
        for (int off = 1; off < 16; off <<= 1) mv = fmaxf(mv, __shfl_xor(mv, off));
        #pragma unroll
        for (int nt = 0; nt < 4; ++nt) {
            const float e = __expf(alpha[nt] - mv);
            const float eo = __shfl_xor(e, 1);
            if (lane < 16 && !(lane & 1))
                lds_ea[32 * w + nt * 8 + (c >> 1)] = pack_bf2(e, eo);
        }
        if (lane == 0) redm[w] = mv;
    }
    // prefetch obs for t=1
    const int id1 = ids[NB + b];
    float obsA[4], obsB[4];
    #pragma unroll
    for (int nt = 0; nt < 4; ++nt)
        obsA[nt] = emit[(size_t)id1 * Z + jbase + nt * 16 + c];

    const f32x4 ZERO4 = {0.f, 0.f, 0.f, 0.f};
    __syncthreads();                                   // staging + ea0 + redm0 ready

    auto STEP = [&](int t, float* obs_u, float* obs_l) {
        const int par = (t - 1) & 1, cur = t & 1;
        // prefetch next obs (full step ahead of its use)
        const int idn = lds_ids[(t < SEQ - 1) ? (t + 1) : (SEQ - 1)];
        #pragma unroll
        for (int nt = 0; nt < 4; ++nt)
            obs_l[nt] = emit[(size_t)idn * Z + jbase + nt * 16 + c];
        // per-source-wave recombination weights (dep: prev step's redm only)
        const float4 rA = *(const float4*)(redm + par * 8);
        const float4 rB = *(const float4*)(redm + par * 8 + 4);
        const float M = fmaxf(fmaxf(fmaxf(rA.x, rA.y), fmaxf(rA.z, rA.w)),
                              fmaxf(fmaxf(rB.x, rB.y), fmaxf(rB.z, rB.w)));
        float wexp[8] = { __expf(rA.x - M), __expf(rA.y - M),
                          __expf(rA.z - M), __expf(rA.w - M),
                          __expf(rB.x - M), __expf(rB.y - M),
                          __expf(rB.z - M), __expf(rB.w - M) };
        float s[4] = {0.f, 0.f, 0.f, 0.f};
        #pragma unroll
        for (int gw = 0; gw < 8; ++gw) {               // source wave gw = kts {2gw, 2gw+1}
            f32x4 acc[4];
            #pragma unroll
            for (int kk = 0; kk < 2; ++kk) {
                const int kt = gw * 2 + kk;
                const bf16x8 af = __builtin_bit_cast(bf16x8,
                    *(const u32x4*)(lds_ea + par * 256 + kt * 16 + g * 4));
                #pragma unroll
                for (int nt = 0; nt < 4; ++nt) {
                    bf16x8 bf;
                    if (kt < KT_LDS)
                        bf = __builtin_bit_cast(bf16x8,
                            *(const u32x4*)(lds_B + ((w * KT_LDS + kt) * 4 + nt) * 256 + lane * 4));
                    else
                        bf = __builtin_bit_cast(bf16x8, breg[kt - KT_LDS][nt]);
                    acc[nt] = __builtin_amdgcn_mfma_f32_16x16x32_bf16(
                        af, bf, kk == 0 ? ZERO4 : acc[nt], 0, 0, 0);
                }
            }
            #pragma unroll
            for (int nt = 0; nt < 4; ++nt)
                s[nt] = fmaf(acc[nt][0], wexp[gw], s[nt]);
        }
        float mv = -INFINITY;
        #pragma unroll
        for (int nt = 0; nt < 4; ++nt) {
            alpha[nt] = obs_u[nt] + adjj[nt] + M + __logf(s[nt]);
            mv = fmaxf(mv, alpha[nt]);
        }
        #pragma unroll
        for (int off = 1; off < 16; off <<= 1) mv = fmaxf(mv, __shfl_xor(mv, off));
        #pragma unroll
        for (int nt = 0; nt < 4; ++nt) {
            const float e = __expf(alpha[nt] - mv);
            const float eo = __shfl_xor(e, 1);
            if (lane < 16 && !(lane & 1))
                lds_ea[cur * 256 + 32 * w + nt * 8 + (c >> 1)] = pack_bf2(e, eo);
        }
        if (lane == 0) redm[cur * 8 + w] = mv;
        __syncthreads();
    };

    for (int tt = 1; tt < SEQ - 1; tt += 2) {
        STEP(tt,     obsA, obsB);
        STEP(tt + 1, obsB, obsA);
    }
    STEP(SEQ - 1, obsA, obsB);                         // t = 255 (odd count)

    // ---- final LSE over all 512 states (redm parity of t=255 is 1)
    const float4 rA = *(const float4*)(redm + 8);
    const float4 rB = *(const float4*)(redm + 12);
    const float Mf = fmaxf(fmaxf(fmaxf(rA.x, rA.y), fmaxf(rA.z, rA.w)),
                           fmaxf(fmaxf(rB.x, rB.y), fmaxf(rB.z, rB.w)));
    float ev = 0.f;
    #pragma unroll
    for (int nt = 0; nt < 4; ++nt) ev += __expf(alpha[nt] - Mf);
    #pragma unroll
    for (int off = 1; off < 16; off <<= 1) ev += __shfl_xor(ev, off);
    if (lane == 0) redf[w] = ev;
    __syncthreads();
    if (tid == 0) {
        float tot = 0.f;
        #pragma unroll
        for (int q = 0; q < 8; ++q) tot += redf[q];
        out[b] = -(Mf + __logf(tot));
    }
}

extern "C" void kernel_launch(void* const* d_in, const int* in_sizes, int n_in,
                              void* d_out, int out_size, void* d_ws, size_t ws_size,
                              hipStream_t stream) {
    const int*   ids  = (const int*)d_in[0];    // [256,64]
    const float* T    = (const float*)d_in[1];  // [512,512]
    const float* pi   = (const float*)d_in[2];  // [512]
    const float* emit = (const float*)d_in[3];  // [10000,512]
    float* out = (float*)d_out;                 // [64]

    float* wsf = (float*)d_ws;
    unsigned* Mbuf   = (unsigned*)wsf;          // 131072 dw = 512 KB bf16 E-matrix
    float*  colLSE   = wsf + 131072;
    float*  mTj      = wsf + 131584;
    float*  pi_eff   = wsf + 132096;
    float*  emit_lse = wsf + 132608;
    float2* em_part  = (float2*)(wsf + 133120); // 32*512 float2

    hipLaunchKernelGGL(k_prepA, dim3(264), dim3(256), 0, stream, T, emit, colLSE, em_part);
    hipLaunchKernelGGL(k_prepB, dim3(513), dim3(512), 0, stream, T, colLSE, em_part, pi,
                       (unsigned short*)Mbuf, mTj, emit_lse, pi_eff);

    const int lds_bytes = 33560 * 4;            // 134240 B
    hipFuncSetAttribute((const void*)k_hmm_scan,
                        hipFuncAttributeMaxDynamicSharedMemorySize, lds_bytes);
    hipLaunchKernelGGL(k_hmm_scan, dim3(64), dim3(512), lds_bytes, stream,
                       ids, emit, Mbuf, mTj, emit_lse, pi_eff, out);
}

// Round 7
// 518.227 us; speedup vs baseline: 1.1306x; 1.1306x over previous
//
#include <hip/hip_runtime.h>
#include <hip/hip_bf16.h>
#include <math.h>

#define Z 512
#define XV 10000
#define SEQ 256
#define NB 64
#define KT_LDS 4               // k-tiles (K=32 each) staged in LDS
#define KT_TOT 16              // total k-tiles

typedef short bf16x8 __attribute__((ext_vector_type(8)));
typedef float f32x4  __attribute__((ext_vector_type(4)));
typedef unsigned u32x4 __attribute__((ext_vector_type(4)));

__device__ __forceinline__ unsigned short bf16_bits(float a) {
    return __builtin_bit_cast(unsigned short, __float2bfloat16(a));
}
__device__ __forceinline__ unsigned pack_bf2(float a, float b) {
    return ((unsigned)bf16_bits(b) << 16) | (unsigned)bf16_bits(a);
}
__device__ __forceinline__ void online_combine(float& m, float& s, float pm, float ps) {
    if (pm > m) { s = s * __expf(m - pm) + ps; m = pm; }
    else        { s = s + ps * __expf(pm - m); }
}

// ---- prepA: blocks 0..7 = column-LSE of T; blocks 8..263 = emit column-LSE partials
__global__ void k_prepA(const float* __restrict__ T, const float* __restrict__ emit,
                        float* __restrict__ colLSE, float2* __restrict__ em_part) {
    __shared__ float ms[256], ss[256];
    const int tid = threadIdx.x;
    const int cl = tid & 63;
    const int r0 = tid >> 6;
    float m = -INFINITY, s = 0.f;
    int outc;
    if (blockIdx.x < 8) {
        const int c = blockIdx.x * 64 + cl;
        for (int r = r0; r < Z; r += 4)
            online_combine(m, s, T[(size_t)r * Z + c], 1.f);
        outc = 0;
    } else {
        const int bb = blockIdx.x - 8;
        const int g = bb & 7, rg = bb >> 3;
        const int c = g * 64 + cl;
        const int rstart = rg * 313;
        const int rend = (rstart + 313 < XV) ? rstart + 313 : XV;
        for (int r = rstart + r0; r < rend; r += 4)
            online_combine(m, s, emit[(size_t)r * Z + c], 1.f);
        outc = 1;
    }
    ms[tid] = m; ss[tid] = s;
    __syncthreads();
    if (tid < 128) {
        m = ms[tid]; s = ss[tid];
        online_combine(m, s, ms[tid + 128], ss[tid + 128]);
        ms[tid] = m; ss[tid] = s;
    }
    __syncthreads();
    if (tid < 64) {
        m = ms[tid]; s = ss[tid];
        online_combine(m, s, ms[tid + 64], ss[tid + 64]);
        if (outc == 0) {
            colLSE[blockIdx.x * 64 + tid] = m + __logf(s);
        } else {
            const int bb = blockIdx.x - 8;
            em_part[(size_t)(bb >> 3) * Z + (bb & 7) * 64 + tid] = make_float2(m, s);
        }
    }
}

// ---- prepB: blocks 0..511 = build bf16 E-matrix row j (+ mTj); block 512 = finalize
__global__ void k_prepB(const float* __restrict__ T, const float* __restrict__ colLSE,
                        const float2* __restrict__ em_part, const float* __restrict__ pi,
                        unsigned short* __restrict__ H, float* __restrict__ mTj,
                        float* __restrict__ emit_lse, float* __restrict__ pi_eff) {
    __shared__ float sh[512];
    const int tid = threadIdx.x;
    if (blockIdx.x < Z) {
        const int j = blockIdx.x;
        const float v = T[(size_t)j * Z + tid] - colLSE[tid];
        float mv = v;
        #pragma unroll
        for (int off = 32; off > 0; off >>= 1) mv = fmaxf(mv, __shfl_xor(mv, off));
        if ((tid & 63) == 0) sh[tid >> 6] = mv;
        __syncthreads();
        float mT = sh[0];
        #pragma unroll
        for (int q = 1; q < 8; ++q) mT = fmaxf(mT, sh[q]);
        H[(size_t)(tid >> 1) * 1024 + 2 * j + (tid & 1)] = bf16_bits(__expf(v - mT));
        if (tid == 0) mTj[j] = mT;
    } else {
        const int z = tid;
        float m = -INFINITY, s = 0.f;
        for (int rg = 0; rg < 32; ++rg) {
            float2 p = em_part[(size_t)rg * Z + z];
            online_combine(m, s, p.x, p.y);
        }
        const float el = m + __logf(s);
        emit_lse[z] = el;
        const float v = pi[z];
        sh[z] = v; __syncthreads();
        for (int off = 256; off > 0; off >>= 1) {
            if (z < off) sh[z] = fmaxf(sh[z], sh[z + off]);
            __syncthreads();
        }
        const float mx = sh[0];
        __syncthreads();
        sh[z] = __expf(v - mx); __syncthreads();
        for (int off = 256; off > 0; off >>= 1) {
            if (z < off) sh[z] += sh[z + off];
            __syncthreads();
        }
        pi_eff[z] = (v - (mx + __logf(sh[0]))) - el;
    }
}

// ---- scan: 64 blocks (one batch each), 512 threads, product-domain state.
// One barrier/step. MFMA = 4 x 16-deep chains, extract once. All scalar
// rescale math (M, f, wc) computed off the critical path.
__global__ void __launch_bounds__(512, 2)
k_hmm_scan(const int* __restrict__ ids, const float* __restrict__ emit,
           const unsigned* __restrict__ Mbuf, const float* __restrict__ mTj,
           const float* __restrict__ emit_lse, const float* __restrict__ pi_eff,
           float* __restrict__ out)
{
    extern __shared__ unsigned dynlds[];
    unsigned* lds_B   = dynlds;                        // 32768 dw = 128 KB
    unsigned* lds_ea  = dynlds + 32768;                // [2][256] dw
    float*    redm    = (float*)(dynlds + 33280);      // [2][8] raw pmax
    float*    redf    = (float*)(dynlds + 33296);      // [8]
    int*      lds_ids = (int*)(dynlds + 33304);        // [256]

    const int b = blockIdx.x;
    const int tid = threadIdx.x;
    const int w = tid >> 6, lane = tid & 63;
    const int g = lane >> 4;                           // k-subgroup 0..3
    const int c = lane & 15;                           // column-in-tile
    const int jbase = 64 * w;

    if (tid < SEQ) lds_ids[tid] = ids[tid * NB + b];

    // ---- stage B: LDS k-tiles (kt 0..3)
    #pragma unroll
    for (int kt = 0; kt < KT_LDS; ++kt)
        #pragma unroll
        for (int nt = 0; nt < 4; ++nt) {
            const unsigned* src = Mbuf + (size_t)(kt * 16 + g * 4) * Z + jbase + nt * 16 + c;
            u32x4 v = { src[0], src[Z], src[2 * Z], src[3 * Z] };
            *(u32x4*)(lds_B + ((w * KT_LDS + kt) * 4 + nt) * 256 + lane * 4) = v;
        }
    // ---- stage B: register k-tiles (kt 4..15)
    u32x4 breg[KT_TOT - KT_LDS][4];
    #pragma unroll
    for (int kt = 0; kt < KT_TOT - KT_LDS; ++kt)
        #pragma unroll
        for (int nt = 0; nt < 4; ++nt) {
            const unsigned* src =
                Mbuf + (size_t)((KT_LDS + kt) * 16 + g * 4) * Z + jbase + nt * 16 + c;
            breg[kt][nt] = (u32x4){ src[0], src[Z], src[2 * Z], src[3 * Z] };
        }

    // ---- init: p0 = exp(alpha0), scale S = 0
    const int id0 = ids[b];
    float adjj[4], p[4];
    float S = 0.f, Sprev = 0.f;
    #pragma unroll
    for (int nt = 0; nt < 4; ++nt) {
        const int j = jbase + nt * 16 + c;
        adjj[nt] = mTj[j] - emit_lse[j];
        p[nt] = __expf(emit[(size_t)id0 * Z + j] + pi_eff[j]);
    }
    {
        #pragma unroll
        for (int nt = 0; nt < 4; ++nt) {
            const float e = p[nt];
            const float eo = __shfl_xor(e, 1);
            if (lane < 16 && !(lane & 1))
                lds_ea[32 * w + nt * 8 + (c >> 1)] = pack_bf2(e, eo);
        }
        float mv = fmaxf(fmaxf(p[0], p[1]), fmaxf(p[2], p[3]));
        #pragma unroll
        for (int off = 1; off < 16; off <<= 1) mv = fmaxf(mv, __shfl_xor(mv, off));
        if (lane == 0) redm[w] = mv;
    }
    // prefetch obs for t=1
    float obsA[4], obsB[4];
    const int id1 = ids[NB + b];
    #pragma unroll
    for (int nt = 0; nt < 4; ++nt)
        obsA[nt] = emit[(size_t)id1 * Z + jbase + nt * 16 + c];

    __syncthreads();                                   // staging + ea0 + redm0 ready

    auto STEP = [&](int t, float* obs_u, float* obs_l) {
        const int par = (t - 1) & 1, cur = t & 1;
        // ---- off-chain prelude (gates only post-MFMA work)
        const float4 rA = *(const float4*)(redm + par * 8);
        const float4 rB = *(const float4*)(redm + par * 8 + 4);
        const float G = fmaxf(fmaxf(fmaxf(rA.x, rA.y), fmaxf(rA.z, rA.w)),
                              fmaxf(fmaxf(rB.x, rB.y), fmaxf(rB.z, rB.w)));
        const float M = Sprev + __logf(G);             // true global max of alpha_{t-1}
        const float f = __expf(S - M);                 // rescale for publishing
        float wc[4];
        #pragma unroll
        for (int nt = 0; nt < 4; ++nt)
            wc[nt] = __expf(obs_u[nt] + adjj[nt]);     // exp(obs+adj), off-chain
        // prefetch next step's obs
        const int idn = lds_ids[(t < SEQ - 1) ? (t + 1) : (SEQ - 1)];
        #pragma unroll
        for (int nt = 0; nt < 4; ++nt)
            obs_l[nt] = emit[(size_t)idn * Z + jbase + nt * 16 + c];

        // ---- MFMA: 4 independent 16-deep chains, extract once
        f32x4 acc[4] = {{0,0,0,0},{0,0,0,0},{0,0,0,0},{0,0,0,0}};
        #pragma unroll
        for (int kt = 0; kt < KT_TOT; ++kt) {
            const bf16x8 af = __builtin_bit_cast(bf16x8,
                *(const u32x4*)(lds_ea + par * 256 + kt * 16 + g * 4));
            #pragma unroll
            for (int nt = 0; nt < 4; ++nt) {
                bf16x8 bf;
                if (kt < KT_LDS)
                    bf = __builtin_bit_cast(bf16x8,
                        *(const u32x4*)(lds_B + ((w * KT_LDS + kt) * 4 + nt) * 256 + lane * 4));
                else
                    bf = __builtin_bit_cast(bf16x8, breg[kt - KT_LDS][nt]);
                acc[nt] = __builtin_amdgcn_mfma_f32_16x16x32_bf16(af, bf, acc[nt], 0, 0, 0);
            }
        }

        // ---- post: p = s*wc ; publish u = p*f (bf16) and raw pmax
        #pragma unroll
        for (int nt = 0; nt < 4; ++nt) p[nt] = acc[nt][0] * wc[nt];
        #pragma unroll
        for (int nt = 0; nt < 4; ++nt) {
            const float u = p[nt] * f;
            const float uo = __shfl_xor(u, 1);
            if (lane < 16 && !(lane & 1))
                lds_ea[cur * 256 + 32 * w + nt * 8 + (c >> 1)] = pack_bf2(u, uo);
        }
        float mv = fmaxf(fmaxf(p[0], p[1]), fmaxf(p[2], p[3]));
        #pragma unroll
        for (int off = 1; off < 16; off <<= 1) mv = fmaxf(mv, __shfl_xor(mv, off));
        if (lane == 0) redm[cur * 8 + w] = mv;
        Sprev = S; S = M;
        __syncthreads();
    };

    for (int tt = 1; tt < SEQ - 1; tt += 2) {
        STEP(tt,     obsA, obsB);
        STEP(tt + 1, obsB, obsA);
    }
    STEP(SEQ - 1, obsA, obsB);                         // t = 255

    // ---- final LSE: p has scale Sprev (= S of step 255 before update)
    float ev = (p[0] + p[1]) + (p[2] + p[3]);
    #pragma unroll
    for (int off = 1; off < 16; off <<= 1) ev += __shfl_xor(ev, off);
    if (lane == 0) redf[w] = ev;
    __syncthreads();
    if (tid == 0) {
        float tot = 0.f;
        #pragma unroll
        for (int q = 0; q < 8; ++q) tot += redf[q];
        out[b] = -(Sprev + __logf(tot));
    }
}

extern "C" void kernel_launch(void* const* d_in, const int* in_sizes, int n_in,
                              void* d_out, int out_size, void* d_ws, size_t ws_size,
                              hipStream_t stream) {
    const int*   ids  = (const int*)d_in[0];    // [256,64]
    const float* T    = (const float*)d_in[1];  // [512,512]
    const float* pi   = (const float*)d_in[2];  // [512]
    const float* emit = (const float*)d_in[3];  // [10000,512]
    float* out = (float*)d_out;                 // [64]

    float* wsf = (float*)d_ws;
    unsigned* Mbuf   = (unsigned*)wsf;          // 131072 dw = 512 KB bf16 E-matrix
    float*  colLSE   = wsf + 131072;
    float*  mTj      = wsf + 131584;
    float*  pi_eff   = wsf + 132096;
    float*  emit_lse = wsf + 132608;
    float2* em_part  = (float2*)(wsf + 133120); // 32*512 float2

    hipLaunchKernelGGL(k_prepA, dim3(264), dim3(256), 0, stream, T, emit, colLSE, em_part);
    hipLaunchKernelGGL(k_prepB, dim3(513), dim3(512), 0, stream, T, colLSE, em_part, pi,
                       (unsigned short*)Mbuf, mTj, emit_lse, pi_eff);

    const int lds_bytes = 33560 * 4;            // 134240 B
    hipFuncSetAttribute((const void*)k_hmm_scan,
                        hipFuncAttributeMaxDynamicSharedMemorySize, lds_bytes);
    hipLaunchKernelGGL(k_hmm_scan, dim3(64), dim3(512), lds_bytes, stream,
                       ids, emit, Mbuf, mTj, emit_lse, pi_eff, out);
}

// Round 10
// 303.471 us; speedup vs baseline: 1.9307x; 1.7077x over previous
//
#include <hip/hip_runtime.h>
#include <math.h>

#define Z 512
#define XV 10000
#define SEQ 256
#define NB 64
#define SCALE_ONE 0x7F7F7F7F   // E8M0 = 2^0 in all 4 bytes

typedef float f32x4 __attribute__((ext_vector_type(4)));
typedef int   i32x8 __attribute__((ext_vector_type(8)));

__device__ __forceinline__ void online_combine(float& m, float& s, float pm, float ps) {
    if (pm > m) { s = s * __expf(m - pm) + ps; m = pm; }
    else        { s = s + ps * __expf(pm - m); }
}

__device__ __forceinline__ float sel4(float a0, float a1, float a2, float a3, int g) {
    const float lo = (g & 1) ? a1 : a0;
    const float hi = (g & 1) ? a3 : a2;
    return (g & 2) ? hi : lo;
}

// ---- prepA: blocks 0..7 = column-LSE of T; blocks 8..263 = emit column-LSE partials
__global__ void k_prepA(const float* __restrict__ T, const float* __restrict__ emit,
                        float* __restrict__ colLSE, float2* __restrict__ em_part) {
    __shared__ float ms[256], ss[256];
    const int tid = threadIdx.x;
    const int cl = tid & 63;
    const int r0 = tid >> 6;
    float m = -INFINITY, s = 0.f;
    int outc;
    if (blockIdx.x < 8) {
        const int c = blockIdx.x * 64 + cl;
        for (int r = r0; r < Z; r += 4)
            online_combine(m, s, T[(size_t)r * Z + c], 1.f);
        outc = 0;
    } else {
        const int bb = blockIdx.x - 8;
        const int g = bb & 7, rg = bb >> 3;
        const int c = g * 64 + cl;
        const int rstart = rg * 313;
        const int rend = (rstart + 313 < XV) ? rstart + 313 : XV;
        for (int r = rstart + r0; r < rend; r += 4)
            online_combine(m, s, emit[(size_t)r * Z + c], 1.f);
        outc = 1;
    }
    ms[tid] = m; ss[tid] = s;
    __syncthreads();
    if (tid < 128) {
        m = ms[tid]; s = ss[tid];
        online_combine(m, s, ms[tid + 128], ss[tid + 128]);
        ms[tid] = m; ss[tid] = s;
    }
    __syncthreads();
    if (tid < 64) {
        m = ms[tid]; s = ss[tid];
        online_combine(m, s, ms[tid + 64], ss[tid + 64]);
        if (outc == 0) {
            colLSE[blockIdx.x * 64 + tid] = m + __logf(s);
        } else {
            const int bb = blockIdx.x - 8;
            em_part[(size_t)(bb >> 3) * Z + (bb & 7) * 64 + tid] = make_float2(m, s);
        }
    }
}

// ---- prepB: blocks 0..511 = fp8 E-matrix row j (tiled for MFMA frags) + mTj;
//      block 512 = finalize emit_lse / pi_eff.
// G8 byte layout: seg = (k>>7)*4 + ((k>>5)&3); addr = seg*16384 + j*32 + (k&31).
// Stored value = fp8_e4m3( exp(T_log[j][k]-mT[j]) * 2^7 ).
__global__ void k_prepB(const float* __restrict__ T, const float* __restrict__ colLSE,
                        const float2* __restrict__ em_part, const float* __restrict__ pi,
                        unsigned char* __restrict__ G8, float* __restrict__ mTj,
                        float* __restrict__ emit_lse, float* __restrict__ pi_eff) {
    __shared__ float sh[512];
    const int tid = threadIdx.x;
    if (blockIdx.x < Z) {
        const int j = blockIdx.x;
        const float v = T[(size_t)j * Z + tid] - colLSE[tid];
        float mv = v;
        #pragma unroll
        for (int off = 32; off > 0; off >>= 1) mv = fmaxf(mv, __shfl_xor(mv, off));
        if ((tid & 63) == 0) sh[tid >> 6] = mv;
        __syncthreads();
        float mT = sh[0];
        #pragma unroll
        for (int q = 1; q < 8; ++q) mT = fmaxf(mT, sh[q]);
        const float e = __expf(v - mT) * 128.f;
        const float eo = __shfl_xor(e, 1);
        if (!(tid & 1)) {
            const int pk = __builtin_amdgcn_cvt_pk_fp8_f32(e, eo, 0, false);
            const int seg = (tid >> 7) * 4 + ((tid >> 5) & 3);
            *(unsigned short*)(G8 + (size_t)seg * 16384 + j * 32 + (tid & 31)) =
                (unsigned short)pk;
        }
        if (tid == 0) mTj[j] = mT;
    } else {
        const int z = tid;
        float m = -INFINITY, s = 0.f;
        for (int rg = 0; rg < 32; ++rg) {
            float2 p = em_part[(size_t)rg * Z + z];
            online_combine(m, s, p.x, p.y);
        }
        const float el = m + __logf(s);
        emit_lse[z] = el;
        const float v = pi[z];
        sh[z] = v; __syncthreads();
        for (int off = 256; off > 0; off >>= 1) {
            if (z < off) sh[z] = fmaxf(sh[z], sh[z + off]);
            __syncthreads();
        }
        const float mx = sh[0];
        __syncthreads();
        sh[z] = __expf(v - mx); __syncthreads();
        for (int off = 256; off > 0; off >>= 1) {
            if (z < off) sh[z] += sh[z + off];
            __syncthreads();
        }
        pi_eff[z] = (v - (mx + __logf(sh[0]))) - el;
    }
}

// ---- scan: 64 blocks (one batch), 512 threads. K=128 MX-fp8 MFMA, whole
// B j-slice in VGPRs (128 dwords/thread). One barrier/step.
// fp8 robustness: each source wave publishes u = p * 2^(7-ex_w) (max lane in
// [64,128)) plus an E8M0 scale byte 127+ex_w; consumers pass it as the HW
// per-32-block A-scale. Exact power-2, immune to inter-step alpha drift.
// f32 state: p_t = exp(alpha_t - M_t), M_t = max alpha_{t-1} = S (running).
__global__ void __launch_bounds__(512, 2)
k_hmm_scan(const int* __restrict__ ids, const float* __restrict__ emit,
           const unsigned char* __restrict__ G8, const float* __restrict__ mTj,
           const float* __restrict__ emit_lse, const float* __restrict__ pi_eff,
           float* __restrict__ out)
{
    __shared__ __align__(16) unsigned char lds_ea[2][512];
    __shared__ float redm[16];
    __shared__ float redf[8];
    __shared__ unsigned char sbyte_l[2][8];
    __shared__ int lds_ids[SEQ];

    const int b = blockIdx.x;
    const int tid = threadIdx.x;
    const int w = tid >> 6, lane = tid & 63;
    const int g = lane >> 4;                 // k-chunk owner (32 k-bytes)
    const int c = lane & 15;                 // column-in-tile
    const int jbase = 64 * w;

    if (tid < SEQ) lds_ids[tid] = ids[tid * NB + b];

    // ---- stage entire B j-slice into registers: breg[kt][nt] = 32 fp8 bytes
    i32x8 breg[4][4];
    #pragma unroll
    for (int kt = 0; kt < 4; ++kt)
        #pragma unroll
        for (int nt = 0; nt < 4; ++nt)
            breg[kt][nt] = *(const i32x8*)(
                G8 + (size_t)(kt * 4 + g) * 16384 + (jbase + nt * 16 + c) * 32);

    // ---- init alpha0
    const int id0 = ids[b];
    float adjc[4], alpha0[4], p[4];
    #pragma unroll
    for (int nt = 0; nt < 4; ++nt) {
        const int j = jbase + nt * 16 + c;
        adjc[nt] = mTj[j] - emit_lse[j] - 14.f * 0.69314718f;   // fold 2^-14
        alpha0[nt] = emit[(size_t)id0 * Z + j] + pi_eff[j];
    }
    float mv0 = fmaxf(fmaxf(alpha0[0], alpha0[1]), fmaxf(alpha0[2], alpha0[3]));
    #pragma unroll
    for (int off = 1; off < 16; off <<= 1) mv0 = fmaxf(mv0, __shfl_xor(mv0, off));
    if (lane == 0) redm[8 + w] = mv0;        // temp slot: per-wave alpha-max
    __syncthreads();
    float M0 = redm[8];
    #pragma unroll
    for (int q = 9; q < 16; ++q) M0 = fmaxf(M0, redm[q]);
    float S = M0;
    {   // p0 = exp(alpha0 - M0); publish with per-wave dynamic exponent
        #pragma unroll
        for (int nt = 0; nt < 4; ++nt) p[nt] = __expf(alpha0[nt] - M0);
        const float pw = __expf(mv0 - M0);   // wave max of p0 (uniform in wave)
        const unsigned mb = __builtin_bit_cast(unsigned, pw);
        const int ex = (int)((mb >> 23) & 255) - 126;           // pw*2^-ex in [0.5,1)
        const float pubf = __builtin_bit_cast(float, (unsigned)(134 - ex) << 23); // 2^(7-ex)
        const float a_g = sel4(p[0], p[1], p[2], p[3], g);
        const float u_g = fminf(a_g * pubf, 440.f);
        const float u_n = __shfl_xor(u_g, 1);
        if (!(c & 1)) {
            const int pk = __builtin_amdgcn_cvt_pk_fp8_f32(u_g, u_n, 0, false);
            *(unsigned short*)(&lds_ea[0][jbase + g * 16 + c]) = (unsigned short)pk;
        }
        if (lane == 0) {
            redm[w] = pw;                                        // raw pmax, scale M0
            sbyte_l[0][w] = (unsigned char)(127 + ex);           // E8M0 2^ex
        }
    }
    // prefetch obs for t=1
    const int id1 = ids[NB + b];
    float obsA[4], obsB[4];
    #pragma unroll
    for (int nt = 0; nt < 4; ++nt)
        obsA[nt] = emit[(size_t)id1 * Z + jbase + nt * 16 + c];
    __syncthreads();                          // ea0 + redm(par0) + sbyte(par0) ready

    auto STEP = [&](int t, float* obs_u, float* obs_l) {
        const int par = (t - 1) & 1, cur = t & 1;
        // ---- off-chain prelude
        const float4 rA = *(const float4*)(redm + par * 8);
        const float4 rB = *(const float4*)(redm + par * 8 + 4);
        const float Gm = fmaxf(fmaxf(fmaxf(rA.x, rA.y), fmaxf(rA.z, rA.w)),
                               fmaxf(fmaxf(rB.x, rB.y), fmaxf(rB.z, rB.w)));
        S += __logf(Gm);                      // S = M_t = true max of alpha_{t-1}
        const float fr = 1.0f / Gm;           // rescale, folded into wc
        float wc[4];
        #pragma unroll
        for (int nt = 0; nt < 4; ++nt)
            wc[nt] = __expf(obs_u[nt] + adjc[nt]) * fr;
        const int idn = lds_ids[(t < SEQ - 1) ? (t + 1) : (SEQ - 1)];
        #pragma unroll
        for (int nt = 0; nt < 4; ++nt)
            obs_l[nt] = emit[(size_t)idn * Z + jbase + nt * 16 + c];
        // per-kt A-scale (source wave 2kt+(g>>1)'s exponent byte, replicated x4)
        int sA[4];
        #pragma unroll
        for (int kt = 0; kt < 4; ++kt)
            sA[kt] = 0x01010101 * (int)sbyte_l[par][2 * kt + (g >> 1)];

        // ---- MFMA: 4 chains x 4 K=128 steps, B from regs, A broadcast from LDS
        f32x4 acc[4] = {{0,0,0,0},{0,0,0,0},{0,0,0,0},{0,0,0,0}};
        #pragma unroll
        for (int kt = 0; kt < 4; ++kt) {
            const i32x8 af = *(const i32x8*)(&lds_ea[par][kt * 128 + g * 32]);
            #pragma unroll
            for (int nt = 0; nt < 4; ++nt)
                acc[nt] = __builtin_amdgcn_mfma_scale_f32_16x16x128_f8f6f4(
                    af, breg[kt][nt], acc[nt], 0, 0, 0, sA[kt], 0, SCALE_ONE);
        }

        // ---- post: p = acc*wc (scale M_t); publish u with per-wave exponent
        #pragma unroll
        for (int nt = 0; nt < 4; ++nt) p[nt] = acc[nt][0] * wc[nt];
        float mv = fmaxf(fmaxf(p[0], p[1]), fmaxf(p[2], p[3]));
        #pragma unroll
        for (int off = 1; off < 16; off <<= 1) mv = fmaxf(mv, __shfl_xor(mv, off));
        const unsigned mb = __builtin_bit_cast(unsigned, mv);
        const int ex = (int)((mb >> 23) & 255) - 126;
        const float pubf = __builtin_bit_cast(float, (unsigned)(134 - ex) << 23);
        const float p_g = sel4(p[0], p[1], p[2], p[3], g);
        const float u_g = fminf(p_g * pubf, 440.f);
        const float u_n = __shfl_xor(u_g, 1);
        if (!(c & 1)) {
            const int pk = __builtin_amdgcn_cvt_pk_fp8_f32(u_g, u_n, 0, false);
            *(unsigned short*)(&lds_ea[cur][jbase + g * 16 + c]) = (unsigned short)pk;
        }
        if (lane == 0) {
            redm[cur * 8 + w] = mv;
            sbyte_l[cur][w] = (unsigned char)(127 + ex);
        }
        __syncthreads();
    };

    for (int tt = 1; tt < SEQ - 1; tt += 2) {
        STEP(tt,     obsA, obsB);
        STEP(tt + 1, obsB, obsA);
    }
    STEP(SEQ - 1, obsA, obsB);               // t = 255

    // ---- final LSE: p = exp(alpha_255 - S)
    float ev = (p[0] + p[1]) + (p[2] + p[3]);
    #pragma unroll
    for (int off = 1; off < 16; off <<= 1) ev += __shfl_xor(ev, off);
    if (lane == 0) redf[w] = ev;
    __syncthreads();
    if (tid == 0) {
        float tot = 0.f;
        #pragma unroll
        for (int q = 0; q < 8; ++q) tot += redf[q];
        out[b] = -(S + __logf(tot));
    }
}

extern "C" void kernel_launch(void* const* d_in, const int* in_sizes, int n_in,
                              void* d_out, int out_size, void* d_ws, size_t ws_size,
                              hipStream_t stream) {
    const int*   ids  = (const int*)d_in[0];    // [256,64]
    const float* T    = (const float*)d_in[1];  // [512,512]
    const float* pi   = (const float*)d_in[2];  // [512]
    const float* emit = (const float*)d_in[3];  // [10000,512]
    float* out = (float*)d_out;                 // [64]

    float* wsf = (float*)d_ws;
    unsigned char* G8 = (unsigned char*)wsf;    // 256 KB fp8 E-matrix (tiled)
    float*  colLSE   = wsf + 65536;
    float*  mTj      = wsf + 66048;
    float*  pi_eff   = wsf + 66560;
    float*  emit_lse = wsf + 67072;
    float2* em_part  = (float2*)(wsf + 67584);  // 32*512 float2

    hipLaunchKernelGGL(k_prepA, dim3(264), dim3(256), 0, stream, T, emit, colLSE, em_part);
    hipLaunchKernelGGL(k_prepB, dim3(513), dim3(512), 0, stream, T, colLSE, em_part, pi,
                       G8, mTj, emit_lse, pi_eff);
    hipLaunchKernelGGL(k_hmm_scan, dim3(64), dim3(512), 0, stream,
                       ids, emit, G8, mTj, emit_lse, pi_eff, out);
}